// Round 1
// baseline (280.187 us; speedup 1.0000x reference)
//
#include <hip/hip_runtime.h>
#include <hip/hip_bf16.h>

#define N_Q 256
#define M_S 1024
#define DD 512
#define HH 512
#define BK 32
#define SA 40   // LDS row stride (elements) for A tile: 80 B, 16B-aligned
#define SB 40   // LDS row stride for B tile

typedef __attribute__((ext_vector_type(8))) short short8;
typedef __attribute__((ext_vector_type(8))) __bf16 bf16x8;
typedef __attribute__((ext_vector_type(16))) float f32x16;

union U8 { short8 s; bf16x8 b; };

__device__ __forceinline__ unsigned short f2bf(float f) {
  // round-to-nearest-even bf16 (inputs are finite; no NaN handling needed)
  unsigned int u = __float_as_uint(f);
  u += 0x7FFFu + ((u >> 16) & 1u);
  return (unsigned short)(u >> 16);
}

// W1 [D][H] fp32 -> w1t [H][D] bf16 (transposed), LDS-tiled for coalescing
__global__ __launch_bounds__(256) void prep_w1t(const float* __restrict__ W1,
                                                unsigned short* __restrict__ w1t) {
  __shared__ float tile[64][65];
  const int h0 = blockIdx.x * 64, d0 = blockIdx.y * 64;
  const int tx = threadIdx.x, ty = threadIdx.y;  // block (64,4)
  for (int i = ty; i < 64; i += 4)
    tile[i][tx] = W1[(d0 + i) * HH + h0 + tx];   // coalesced read along h
  __syncthreads();
  for (int i = ty; i < 64; i += 4)
    w1t[(h0 + i) * DD + d0 + tx] = f2bf(tile[tx][i]);  // coalesced write along d
}

// Stage next K-slab into registers: diff |e-s| -> bf16 (8 elems) + 4 x bf16x8 of W1t
__device__ __forceinline__ void load_stage(const float* erow, const float* srow,
                                           const unsigned short* w1t, int k0,
                                           int aq, int rh, short8& av, short8 bv[4]) {
  const float4* e4 = (const float4*)(erow + k0 + aq * 8);
  const float4* s4 = (const float4*)(srow + k0 + aq * 8);
  float4 e0 = e4[0], e1 = e4[1], s0 = s4[0], s1 = s4[1];
  short8 v;
  v[0] = (short)f2bf(fabsf(e0.x - s0.x));
  v[1] = (short)f2bf(fabsf(e0.y - s0.y));
  v[2] = (short)f2bf(fabsf(e0.z - s0.z));
  v[3] = (short)f2bf(fabsf(e0.w - s0.w));
  v[4] = (short)f2bf(fabsf(e1.x - s1.x));
  v[5] = (short)f2bf(fabsf(e1.y - s1.y));
  v[6] = (short)f2bf(fabsf(e1.z - s1.z));
  v[7] = (short)f2bf(fabsf(e1.w - s1.w));
  av = v;
#pragma unroll
  for (int j = 0; j < 4; ++j)
    bv[j] = *(const short8*)(w1t + (j * 128 + rh) * DD + k0 + aq * 8);
}

__global__ __launch_bounds__(512, 2) void support_kernel(
    const float* __restrict__ emb, const float* __restrict__ sup,
    const unsigned short* __restrict__ w1t, const float* __restrict__ b1,
    const float* __restrict__ W2, const float* __restrict__ b2,
    float* __restrict__ out) {
  __shared__ short As[128 * SA];  // 10240 B
  __shared__ short Bs[512 * SB];  // 40960 B

  const int tid = threadIdx.x;
  const int lane = tid & 63;
  const int wid = tid >> 6;       // 0..7
  const int wm = wid & 1;         // pair half (64 pairs each)
  const int wh = wid >> 1;        // h quarter (128 h each)
  const int l31 = lane & 31;
  const int khalf = lane >> 5;

  const int m0 = blockIdx.x * 16;
  const int n0 = blockIdx.y * 8;

  // staging mapping: thread -> (pair row, k-chunk) and (B row base, k-chunk)
  const int ap = tid >> 2;        // 0..127 : A pair row AND B row base
  const int aq = tid & 3;         // 0..3   : 8-element k chunk
  const float* erow = emb + (n0 + (ap >> 4)) * DD;  // wave-uniform n row
  const float* srow = sup + (m0 + (ap & 15)) * DD;

  f32x16 acc[2][4] = {};

  short8 av;
  short8 bv[4];
  load_stage(erow, srow, w1t, 0, aq, ap, av, bv);

  for (int it = 0; it < DD / BK; ++it) {
    __syncthreads();  // LDS free (previous compute done)
    *(short8*)&As[ap * SA + aq * 8] = av;
#pragma unroll
    for (int j = 0; j < 4; ++j)
      *(short8*)&Bs[(j * 128 + ap) * SB + aq * 8] = bv[j];
    __syncthreads();  // tiles visible

    if (it + 1 < DD / BK)  // prefetch next slab; overlaps with MFMA below
      load_stage(erow, srow, w1t, (it + 1) * BK, aq, ap, av, bv);

#pragma unroll
    for (int kk = 0; kk < 2; ++kk) {
      U8 a0, a1, bf[4];
      a0.s = *(const short8*)&As[(wm * 64 + 0 + l31) * SA + kk * 16 + khalf * 8];
      a1.s = *(const short8*)&As[(wm * 64 + 32 + l31) * SA + kk * 16 + khalf * 8];
#pragma unroll
      for (int tj = 0; tj < 4; ++tj)
        bf[tj].s = *(const short8*)&Bs[(wh * 128 + tj * 32 + l31) * SB + kk * 16 + khalf * 8];
#pragma unroll
      for (int tj = 0; tj < 4; ++tj) {
        acc[0][tj] = __builtin_amdgcn_mfma_f32_32x32x16_bf16(a0.b, bf[tj].b, acc[0][tj], 0, 0, 0);
        acc[1][tj] = __builtin_amdgcn_mfma_f32_32x32x16_bf16(a1.b, bf[tj].b, acc[1][tj], 0, 0, 0);
      }
    }
  }

  // ---- epilogue: out[nm] = sigmoid( sum_h relu(C+b1[h]) * W2[h] + b2 ) ----
  float b1v[4], w2v[4];
#pragma unroll
  for (int tj = 0; tj < 4; ++tj) {
    int h = wh * 128 + tj * 32 + l31;   // C/D: col = lane&31
    b1v[tj] = b1[h];
    w2v[tj] = W2[h];
  }
  __syncthreads();                      // all LDS reads done; reuse As
  float* psums = (float*)As;            // [128 pairs][4 wave-h-groups]
#pragma unroll
  for (int ti = 0; ti < 2; ++ti) {
#pragma unroll
    for (int r = 0; r < 16; ++r) {
      float s = 0.f;
#pragma unroll
      for (int tj = 0; tj < 4; ++tj) {
        float c = acc[ti][tj][r] + b1v[tj];
        s += fmaxf(c, 0.f) * w2v[tj];
      }
      // reduce across the 32 h-columns held by lanes (same khalf half)
      s += __shfl_xor(s, 1, 64);
      s += __shfl_xor(s, 2, 64);
      s += __shfl_xor(s, 4, 64);
      s += __shfl_xor(s, 8, 64);
      s += __shfl_xor(s, 16, 64);
      int row = (r & 3) + 8 * (r >> 2) + 4 * khalf;  // C/D row mapping (m74/m101)
      if (l31 == 0) psums[(wm * 64 + ti * 32 + row) * 4 + wh] = s;
    }
  }
  __syncthreads();
  if (tid < 128) {
    float t = psums[tid * 4 + 0] + psums[tid * 4 + 1] +
              psums[tid * 4 + 2] + psums[tid * 4 + 3] + b2[0];
    float sig = 1.f / (1.f + __expf(-t));
    out[(n0 + (tid >> 4)) * M_S + m0 + (tid & 15)] = sig;
  }
}

extern "C" void kernel_launch(void* const* d_in, const int* in_sizes, int n_in,
                              void* d_out, int out_size, void* d_ws, size_t ws_size,
                              hipStream_t stream) {
  const float* emb = (const float*)d_in[0];
  const float* sup = (const float*)d_in[1];
  const float* W1  = (const float*)d_in[2];
  const float* b1  = (const float*)d_in[3];
  const float* W2  = (const float*)d_in[4];
  const float* b2  = (const float*)d_in[5];
  float* out = (float*)d_out;
  unsigned short* w1t = (unsigned short*)d_ws;  // 512*512*2 = 512 KB

  prep_w1t<<<dim3(HH / 64, DD / 64), dim3(64, 4), 0, stream>>>(W1, w1t);
  support_kernel<<<dim3(M_S / 16, N_Q / 8), 512, 0, stream>>>(emb, sup, w1t, b1, W2, b2, out);
}